// Round 8
// baseline (535.831 us; speedup 1.0000x reference)
//
#include <hip/hip_runtime.h>
#include <stdint.h>

// Problem constants (RelationalAttentionLayer)
#define N_NODES 50000
#define DIM     128
#define HEADS   4
#define HDIM    512      // HEADS * DIM
#define NREL    3
#define NEDGE   50000    // edges per relation
#define NETOT   150000   // total edges
#define NKEYS   150000   // NREL * N_NODES keys for per-rel CSR
#define NB2     586      // ceil(NKEYS/256)
#define FLAG_CAP 32768

constexpr float EPS_F  = 1e-10f;
constexpr float SCALE  = 0.044194173824159216f;  // 1/sqrt(512)
constexpr float TAU    = 0.005f;                 // exact-repair band

typedef unsigned short ushort_t;
typedef __attribute__((ext_vector_type(8))) short  short8;
typedef __attribute__((ext_vector_type(4))) unsigned short ushort4v;
typedef __attribute__((ext_vector_type(4))) float  f32x4;

__device__ __forceinline__ float b2f(ushort_t u) {
    unsigned int v = ((unsigned int)u) << 16;
    float f; __builtin_memcpy(&f, &v, 4); return f;
}
__device__ __forceinline__ ushort_t f2b(float f) {
    unsigned int v; __builtin_memcpy(&v, &f, 4);
    unsigned int r = v + 0x7FFFu + ((v >> 16) & 1u);   // RNE
    return (ushort_t)(r >> 16);
}

#define LDSTRIDE 40   // ushort stride per 32-elem k-row (80B; 16B slots; 2-way alias free)

// ---------------------------------------------------------------------------
// bf16 MFMA GEMM (final out-GEMM): C[M,N] = A[M,K] @ Bt[N][K]^T. BM=64.
// ---------------------------------------------------------------------------
template <int OUTMODE, int BM>
__global__ __launch_bounds__(256) void gemm_mfma(const ushort_t* __restrict__ A,
                                                 const ushort_t* __restrict__ Bt,
                                                 void* __restrict__ Cv,
                                                 int M, int K, int ldc)
{
    constexpr int MFR = BM / 32;
    constexpr int ACH = BM * 4 / 256;

    __shared__ ushort_t As[BM * LDSTRIDE];
    __shared__ ushort_t Bs[128 * LDSTRIDE];

    const int tid = threadIdx.x;
    const int w = tid >> 6, l = tid & 63;
    const int bm = blockIdx.x, bn = blockIdx.y;
    const int wr = w >> 1, wc = w & 1;

    int sa_ro[ACH]; size_t sa_o[ACH];
#pragma unroll
    for (int i = 0; i < ACH; ++i) {
        int c = tid + 256 * i;
        int row = c >> 2, slot = c & 3;
        sa_ro[i] = row * LDSTRIDE + slot * 8;
        int grow = bm * BM + row; if (grow >= M) grow = M - 1;
        sa_o[i] = (size_t)grow * K + slot * 8;
    }
    int sb_ro[2]; size_t sb_o[2];
#pragma unroll
    for (int i = 0; i < 2; ++i) {
        int c = tid + 256 * i;
        int row = c >> 2, slot = c & 3;
        sb_ro[i] = row * LDSTRIDE + slot * 8;
        sb_o[i] = (size_t)(bn * 128 + row) * K + slot * 8;
    }

    int a_off[MFR], b_off[4];
#pragma unroll
    for (int mi = 0; mi < MFR; ++mi)
        a_off[mi] = (wr * (BM / 2) + mi * 16 + (l & 15)) * LDSTRIDE + (l >> 4) * 8;
#pragma unroll
    for (int ni = 0; ni < 4; ++ni)
        b_off[ni] = (wc * 64 + ni * 16 + (l & 15)) * LDSTRIDE + (l >> 4) * 8;

    f32x4 acc[MFR][4] = {};

    short8 av[ACH], bv[2];
#pragma unroll
    for (int i = 0; i < ACH; ++i) av[i] = *(const short8*)(A + sa_o[i]);
#pragma unroll
    for (int i = 0; i < 2; ++i)   bv[i] = *(const short8*)(Bt + sb_o[i]);

    for (int kk = 0; kk < K; kk += 32) {
        __syncthreads();
#pragma unroll
        for (int i = 0; i < ACH; ++i) *(short8*)&As[sa_ro[i]] = av[i];
#pragma unroll
        for (int i = 0; i < 2; ++i)   *(short8*)&Bs[sb_ro[i]] = bv[i];
        __syncthreads();

        if (kk + 32 < K) {
#pragma unroll
            for (int i = 0; i < ACH; ++i) av[i] = *(const short8*)(A + sa_o[i] + kk + 32);
#pragma unroll
            for (int i = 0; i < 2; ++i)   bv[i] = *(const short8*)(Bt + sb_o[i] + kk + 32);
        }

        short8 af[MFR], bfr[4];
#pragma unroll
        for (int mi = 0; mi < MFR; ++mi) af[mi]  = *(const short8*)&As[a_off[mi]];
#pragma unroll
        for (int ni = 0; ni < 4; ++ni)   bfr[ni] = *(const short8*)&Bs[b_off[ni]];

#pragma unroll
        for (int mi = 0; mi < MFR; ++mi)
#pragma unroll
            for (int ni = 0; ni < 4; ++ni)
                acc[mi][ni] = __builtin_amdgcn_mfma_f32_16x16x32_bf16(af[mi], bfr[ni], acc[mi][ni], 0, 0, 0);
    }

#pragma unroll
    for (int mi = 0; mi < MFR; ++mi)
#pragma unroll
        for (int j = 0; j < 4; ++j) {
            int row = bm * BM + wr * (BM / 2) + mi * 16 + (l >> 4) * 4 + j;
            if (row < M) {
#pragma unroll
                for (int ni = 0; ni < 4; ++ni) {
                    int col = bn * 128 + wc * 64 + ni * 16 + (l & 15);
                    if (OUTMODE == 1)
                        ((ushort_t*)Cv)[(size_t)row * ldc + col] = f2b(acc[mi][ni][j]);
                    else
                        ((float*)Cv)[(size_t)row * ldc + col] = acc[mi][ni][j];
                }
            }
        }
}

// ---------------------------------------------------------------------------
// Split-bf16 q-GEMM, A in LDS, B (WQt hi/lo, L2-resident) from global.
// Output HEAD-MAJOR: q4[h][N][128] f32. grid (MB128, 4 heads).
// ---------------------------------------------------------------------------
__global__ __launch_bounds__(256) void gemm_split_q(const ushort_t* __restrict__ Ahg,
                                                    const ushort_t* __restrict__ Alg,
                                                    const ushort_t* __restrict__ Bhg,
                                                    const ushort_t* __restrict__ Blg,
                                                    float* __restrict__ q4, int M)
{
    __shared__ ushort_t Ah[128 * LDSTRIDE], Al[128 * LDSTRIDE];

    const int tid = threadIdx.x;
    const int w = tid >> 6, l = tid & 63;
    const int bm = blockIdx.x, bn = blockIdx.y;   // bn = head
    const int wr = w >> 1, wc = w & 1;

    int s_ro[2]; size_t s_ao[2];
#pragma unroll
    for (int i = 0; i < 2; ++i) {
        int c = tid + 256 * i;
        int row = c >> 2, slot = c & 3;
        s_ro[i] = row * LDSTRIDE + slot * 8;
        int grow = bm * 128 + row; if (grow >= M) grow = M - 1;
        s_ao[i] = (size_t)grow * 128 + slot * 8;
    }

    int a_off[4]; size_t b_go[4];
#pragma unroll
    for (int mi = 0; mi < 4; ++mi)
        a_off[mi] = (wr * 64 + mi * 16 + (l & 15)) * LDSTRIDE + (l >> 4) * 8;
#pragma unroll
    for (int ni = 0; ni < 4; ++ni)
        b_go[ni] = (size_t)(bn * 128 + wc * 64 + ni * 16 + (l & 15)) * 128 + (l >> 4) * 8;

    f32x4 acc[4][4] = {};

    short8 vah[2], val[2];
#pragma unroll
    for (int i = 0; i < 2; ++i) {
        vah[i] = *(const short8*)(Ahg + s_ao[i]);
        val[i] = *(const short8*)(Alg + s_ao[i]);
    }

    for (int kk = 0; kk < 128; kk += 32) {
        __syncthreads();
#pragma unroll
        for (int i = 0; i < 2; ++i) {
            *(short8*)&Ah[s_ro[i]] = vah[i];
            *(short8*)&Al[s_ro[i]] = val[i];
        }
        __syncthreads();

        if (kk + 32 < 128) {
#pragma unroll
            for (int i = 0; i < 2; ++i) {
                vah[i] = *(const short8*)(Ahg + s_ao[i] + kk + 32);
                val[i] = *(const short8*)(Alg + s_ao[i] + kk + 32);
            }
        }

        short8 bh[4], bl[4];
#pragma unroll
        for (int ni = 0; ni < 4; ++ni) {
            bh[ni] = *(const short8*)(Bhg + b_go[ni] + kk);
            bl[ni] = *(const short8*)(Blg + b_go[ni] + kk);
        }
        short8 ah[4], al[4];
#pragma unroll
        for (int mi = 0; mi < 4; ++mi) { ah[mi] = *(const short8*)&Ah[a_off[mi]];
                                         al[mi] = *(const short8*)&Al[a_off[mi]]; }
#pragma unroll
        for (int mi = 0; mi < 4; ++mi)
#pragma unroll
            for (int ni = 0; ni < 4; ++ni) {
                acc[mi][ni] = __builtin_amdgcn_mfma_f32_16x16x32_bf16(ah[mi], bh[ni], acc[mi][ni], 0, 0, 0);
                acc[mi][ni] = __builtin_amdgcn_mfma_f32_16x16x32_bf16(ah[mi], bl[ni], acc[mi][ni], 0, 0, 0);
                acc[mi][ni] = __builtin_amdgcn_mfma_f32_16x16x32_bf16(al[mi], bh[ni], acc[mi][ni], 0, 0, 0);
            }
    }

#pragma unroll
    for (int mi = 0; mi < 4; ++mi)
#pragma unroll
        for (int j = 0; j < 4; ++j) {
            int row = bm * 128 + wr * 64 + mi * 16 + (l >> 4) * 4 + j;
            if (row < M) {
#pragma unroll
                for (int ni = 0; ni < 4; ++ni) {
                    int colw = wc * 64 + ni * 16 + (l & 15);
                    q4[((size_t)bn * M + row) * 128 + colw] = acc[mi][ni][j];
                }
            }
        }
}

// ---------------------------------------------------------------------------
// scores v3: dst-sorted edges, A (x hi/lo gathered) in LDS, W frags from
// global (L2), q head-major streamed by sorted dst. grid (MB128, 4, 3).
// ---------------------------------------------------------------------------
__global__ __launch_bounds__(256) void scores_v3(const ushort_t* __restrict__ xh,
                                                 const ushort_t* __restrict__ xl,
                                                 const ushort_t* __restrict__ WKth,
                                                 const ushort_t* __restrict__ WKtl,
                                                 const float* __restrict__ q4,
                                                 const int* __restrict__ src_s,
                                                 const int* __restrict__ dst_s,
                                                 float* __restrict__ scores,
                                                 int* __restrict__ flagcnt,
                                                 int* __restrict__ fids)
{
    __shared__ ushort_t Ah[128 * LDSTRIDE], Al[128 * LDSTRIDE];
    __shared__ float sc_red[128][2];

    const int tid = threadIdx.x;
    const int w = tid >> 6, l = tid & 63;
    const int bm = blockIdx.x;
    const int nc = blockIdx.y;          // head
    const int r  = blockIdx.z;          // relation
    const int wr = w >> 1, wc = w & 1;
    const int base = r * NEDGE;         // sorted-position base for this rel

    const ushort_t* Wh = WKth + (size_t)r * HDIM * DIM;
    const ushort_t* Wl = WKtl + (size_t)r * HDIM * DIM;

    int s_ro[2]; size_t s_ao[2];
#pragma unroll
    for (int i = 0; i < 2; ++i) {
        int c = tid + 256 * i;
        int row = c >> 2, slot = c & 3;
        s_ro[i] = row * LDSTRIDE + slot * 8;
        int el = bm * 128 + row; if (el >= NEDGE) el = NEDGE - 1;
        s_ao[i] = (size_t)src_s[base + el] * 128 + slot * 8;
    }

    int a_off[4]; size_t b_go[4];
#pragma unroll
    for (int mi = 0; mi < 4; ++mi)
        a_off[mi] = (wr * 64 + mi * 16 + (l & 15)) * LDSTRIDE + (l >> 4) * 8;
#pragma unroll
    for (int ni = 0; ni < 4; ++ni)
        b_go[ni] = (size_t)(nc * 128 + wc * 64 + ni * 16 + (l & 15)) * 128 + (l >> 4) * 8;

    f32x4 acc[4][4] = {};

    short8 vah[2], val[2];
#pragma unroll
    for (int i = 0; i < 2; ++i) {
        vah[i] = *(const short8*)(xh + s_ao[i]);
        val[i] = *(const short8*)(xl + s_ao[i]);
    }

    for (int kk = 0; kk < 128; kk += 32) {
        __syncthreads();
#pragma unroll
        for (int i = 0; i < 2; ++i) {
            *(short8*)&Ah[s_ro[i]] = vah[i];
            *(short8*)&Al[s_ro[i]] = val[i];
        }
        __syncthreads();

        if (kk + 32 < 128) {
#pragma unroll
            for (int i = 0; i < 2; ++i) {
                vah[i] = *(const short8*)(xh + s_ao[i] + kk + 32);
                val[i] = *(const short8*)(xl + s_ao[i] + kk + 32);
            }
        }

        short8 bh[4], bl[4];
#pragma unroll
        for (int ni = 0; ni < 4; ++ni) {
            bh[ni] = *(const short8*)(Wh + b_go[ni] + kk);
            bl[ni] = *(const short8*)(Wl + b_go[ni] + kk);
        }
        short8 ah[4], al[4];
#pragma unroll
        for (int mi = 0; mi < 4; ++mi) { ah[mi] = *(const short8*)&Ah[a_off[mi]];
                                         al[mi] = *(const short8*)&Al[a_off[mi]]; }
#pragma unroll
        for (int mi = 0; mi < 4; ++mi)
#pragma unroll
            for (int ni = 0; ni < 4; ++ni) {
                acc[mi][ni] = __builtin_amdgcn_mfma_f32_16x16x32_bf16(ah[mi], bh[ni], acc[mi][ni], 0, 0, 0);
                acc[mi][ni] = __builtin_amdgcn_mfma_f32_16x16x32_bf16(ah[mi], bl[ni], acc[mi][ni], 0, 0, 0);
                acc[mi][ni] = __builtin_amdgcn_mfma_f32_16x16x32_bf16(al[mi], bh[ni], acc[mi][ni], 0, 0, 0);
            }
    }

    // dot k-fragments with q4[nc][dst]
#pragma unroll
    for (int mi = 0; mi < 4; ++mi)
#pragma unroll
        for (int j = 0; j < 4; ++j) {
            int e_loc = wr * 64 + mi * 16 + (l >> 4) * 4 + j;
            int e = bm * 128 + e_loc; int ec = (e < NEDGE) ? e : NEDGE - 1;
            int d = dst_s[base + ec];
            const float* qr = q4 + ((size_t)nc * N_NODES + d) * 128 + wc * 64 + (l & 15);
            float p = acc[mi][0][j] * qr[0]  + acc[mi][1][j] * qr[16]
                    + acc[mi][2][j] * qr[32] + acc[mi][3][j] * qr[48];
            p += __shfl_xor(p, 1); p += __shfl_xor(p, 2);
            p += __shfl_xor(p, 4); p += __shfl_xor(p, 8);
            if ((l & 15) == 0) sc_red[e_loc][wc] = p;
        }
    __syncthreads();

    if (tid < 128) {
        int e = bm * 128 + tid;
        if (e < NEDGE) {
            float s = (sc_red[tid][0] + sc_red[tid][1]) * SCALE;
            int idx = (base + e) * HEADS + nc;
            scores[idx] = s;
            if (fabsf(s) < TAU) {
                int pos = atomicAdd(flagcnt, 1);
                if (pos < FLAG_CAP) fids[pos] = idx;
            }
        }
    }
}

// ---------------------------------------------------------------------------
// Exact f32 repair of near-zero scores (sorted-position indexing).
// ---------------------------------------------------------------------------
__global__ __launch_bounds__(256) void repair_kernel(const float* __restrict__ x,
                                                     const float* __restrict__ WQ,
                                                     const float* __restrict__ WK,
                                                     const int* __restrict__ src_s,
                                                     const int* __restrict__ dst_s,
                                                     const int* __restrict__ flagcnt,
                                                     const int* __restrict__ fids,
                                                     float* __restrict__ scores)
{
    int wid = blockIdx.x * 4 + (threadIdx.x >> 6);
    int l = threadIdx.x & 63;
    int nf = *flagcnt; if (nf > FLAG_CAP) nf = FLAG_CAP;
    if (wid >= nf) return;
    int p = fids[wid];
    int h = p & 3; int pos = p >> 2; int r = pos / NEDGE;
    int s = src_s[pos], d = dst_s[pos];
    const float* xs = x + (size_t)s * DIM;
    const float* xd = x + (size_t)d * DIM;
    const float* wq = WQ + h * DIM;
    const float* wk = WK + (size_t)r * DIM * HDIM + h * DIM;

    float tot = 0.f;
#pragma unroll 1
    for (int j = 0; j < 2; ++j) {
        int c = j * 64 + l;
        float qc = 0.f, kc = 0.f;
        for (int dd = 0; dd < DIM; ++dd) {
            qc = fmaf(xd[dd], wq[(size_t)dd * HDIM + c], qc);
            kc = fmaf(xs[dd], wk[(size_t)dd * HDIM + c], kc);
        }
        tot = fmaf(qc, kc, tot);
    }
    tot += __shfl_xor(tot, 1);  tot += __shfl_xor(tot, 2);
    tot += __shfl_xor(tot, 4);  tot += __shfl_xor(tot, 8);
    tot += __shfl_xor(tot, 16); tot += __shfl_xor(tot, 32);
    if (l == 0) scores[p] = tot * SCALE;
}

// ---------------------------------------------------------------------------
// numer = relu(s)^2 + eps (in place) ; atomic denom (dst_s sequential)
// ---------------------------------------------------------------------------
__global__ __launch_bounds__(256) void numer_denom(float* __restrict__ scores,
                                                   const int* __restrict__ dst_s,
                                                   float* __restrict__ denom)
{
    int p = blockIdx.x * 256 + threadIdx.x;
    if (p < NETOT * HEADS) {
        float s = scores[p];
        float m = fmaxf(s, 0.f);
        float nu = m * m + EPS_F;
        scores[p] = nu;
        atomicAdd(&denom[dst_s[p >> 2] * HEADS + (p & 3)], nu);
    }
}

// ---------------------------------------------------------------------------
// prep kernels
// ---------------------------------------------------------------------------
__global__ __launch_bounds__(256) void cvt_x_split(const float* __restrict__ x,
                                                   ushort_t* __restrict__ xh,
                                                   ushort_t* __restrict__ xl)
{
    int i = (blockIdx.x * 256 + threadIdx.x) * 4;
    float4 v = *reinterpret_cast<const float4*>(x + i);
    ushort_t h0 = f2b(v.x), h1 = f2b(v.y), h2 = f2b(v.z), h3 = f2b(v.w);
    ushort4v oh = {h0, h1, h2, h3};
    ushort4v ol = {f2b(v.x - b2f(h0)), f2b(v.y - b2f(h1)),
                   f2b(v.z - b2f(h2)), f2b(v.w - b2f(h3))};
    *reinterpret_cast<ushort4v*>(xh + i) = oh;
    *reinterpret_cast<ushort4v*>(xl + i) = ol;
}

// split transpose: hi/lo pair. out[C][R] = transpose(in[R][C] f32)
__global__ __launch_bounds__(256) void transpose_cvt_split(const float* __restrict__ in,
                                                           ushort_t* __restrict__ oh,
                                                           ushort_t* __restrict__ ol,
                                                           int R, int C)
{
    __shared__ float t[32][33];
    int x = threadIdx.x & 31, y0 = threadIdx.x >> 5;
    int br = blockIdx.y, bc = blockIdx.x;
#pragma unroll
    for (int k = 0; k < 4; ++k)
        t[y0 + k * 8][x] = in[(size_t)(br * 32 + y0 + k * 8) * C + bc * 32 + x];
    __syncthreads();
#pragma unroll
    for (int k = 0; k < 4; ++k) {
        int c = bc * 32 + y0 + k * 8;
        float v = t[x][y0 + k * 8];
        ushort_t hv = f2b(v);
        oh[(size_t)c * R + br * 32 + x] = hv;
        ol[(size_t)c * R + br * 32 + x] = f2b(v - b2f(hv));
    }
}

// ---------------------------------------------------------------------------
// W2 composite: W2t[j][h*384 + r*128 + d] = sum_c WV[r][d][h*128+c] * WO[h*128+c][j]
// ---------------------------------------------------------------------------
__global__ __launch_bounds__(256) void w2_kernel(const float* __restrict__ WV,
                                                 const float* __restrict__ WO,
                                                 ushort_t* __restrict__ W2t)
{
    int j = threadIdx.x & 127;
    int hk = blockIdx.x * 2 + (threadIdx.x >> 7);   // 0..1535
    int h = hk / 384, kk = hk % 384;
    int r = kk >> 7, d = kk & 127;
    const float* wv = WV + (size_t)r * DIM * HDIM + (size_t)d * HDIM + h * DIM;
    const float* wo = WO + (size_t)(h * DIM) * DIM + j;
    float acc = 0.f;
#pragma unroll 4
    for (int c = 0; c < DIM; ++c)
        acc = fmaf(wv[c], wo[(size_t)c * DIM], acc);
    W2t[(size_t)j * 1536 + hk] = f2b(acc);
}

// ---------------------------------------------------------------------------
// Per-rel CSR over flattened keys (r*N + dst): count, 3-level scan, fill.
// ---------------------------------------------------------------------------
__global__ __launch_bounds__(256) void csr_count3(const int* __restrict__ dst, int* __restrict__ cnt3)
{
    int e = blockIdx.x * 256 + threadIdx.x;
    if (e < NETOT) {
        int r = e / NEDGE;
        atomicAdd(&cnt3[r * N_NODES + dst[e]], 1);
    }
}

__global__ __launch_bounds__(256) void scan_blksum(const int* __restrict__ cnt,
                                                   int* __restrict__ blksum)
{
    __shared__ int red[4];
    int tid = threadIdx.x, lane = tid & 63, wave = tid >> 6;
    int i = blockIdx.x * 256 + tid;
    int v = (i < NKEYS) ? cnt[i] : 0;
#pragma unroll
    for (int off = 32; off > 0; off >>= 1) v += __shfl_down(v, off);
    if (lane == 0) red[wave] = v;
    __syncthreads();
    if (tid == 0) blksum[blockIdx.x] = red[0] + red[1] + red[2] + red[3];
}

__global__ __launch_bounds__(1024) void scan_top1024(const int* __restrict__ blksum,
                                                     int* __restrict__ blkoff,
                                                     int* __restrict__ row_ptr3)
{
    __shared__ int s[1024];
    int t = threadIdx.x;
    int v = (t < NB2) ? blksum[t] : 0;
    s[t] = v;
    __syncthreads();
    for (int off = 1; off < 1024; off <<= 1) {
        int u = (t >= off) ? s[t - off] : 0;
        __syncthreads();
        s[t] += u;
        __syncthreads();
    }
    if (t < NB2) blkoff[t] = s[t] - v;   // exclusive
    if (t == NB2 - 1) row_ptr3[NKEYS] = s[t];
}

__global__ __launch_bounds__(256) void scan_fin(const int* __restrict__ cnt,
                                                const int* __restrict__ blkoff,
                                                int* __restrict__ row_ptr3,
                                                int* __restrict__ cursor3)
{
    __shared__ int s[256];
    int t = threadIdx.x, i = blockIdx.x * 256 + t;
    int v = (i < NKEYS) ? cnt[i] : 0;
    s[t] = v;
    __syncthreads();
    for (int off = 1; off < 256; off <<= 1) {
        int u = (t >= off) ? s[t - off] : 0;
        __syncthreads();
        s[t] += u;
        __syncthreads();
    }
    if (i < NKEYS) {
        int val = blkoff[blockIdx.x] + s[t] - v;
        row_ptr3[i] = val;
        cursor3[i]  = val;
    }
}

__global__ __launch_bounds__(256) void csr_fill3(const int* __restrict__ src,
                                                 const int* __restrict__ dst,
                                                 int* __restrict__ cursor3,
                                                 int* __restrict__ src_s,
                                                 int* __restrict__ dst_s)
{
    int e = blockIdx.x * 256 + threadIdx.x;
    if (e < NETOT) {
        int r = e / NEDGE;
        int d = dst[e];
        int pos = atomicAdd(&cursor3[r * N_NODES + d], 1);
        src_s[pos] = src[e];
        dst_s[pos] = d;
    }
}

// ---------------------------------------------------------------------------
// agg_all v2: one wave per node; per-rel CSR ranges; sequential src_s/numer_s.
// ---------------------------------------------------------------------------
__global__ __launch_bounds__(256) void agg_all(const float* __restrict__ x,
                                               const float* __restrict__ numer,
                                               const float* __restrict__ denom,
                                               const int* __restrict__ row_ptr3,
                                               const int* __restrict__ src_s,
                                               ushort_t* __restrict__ y)
{
    const int wave = threadIdx.x >> 6, lane = threadIdx.x & 63;
    const int n = blockIdx.x * 4 + wave;
    if (n >= N_NODES) return;

    float4 dn = *reinterpret_cast<const float4*>(&denom[n * HEADS]);
    float di[HEADS] = {1.f / dn.x, 1.f / dn.y, 1.f / dn.z, 1.f / dn.w};

    float acc[NREL][HEADS][2] = {};

#pragma unroll
    for (int r = 0; r < NREL; ++r) {
        int beg = row_ptr3[r * N_NODES + n];
        int end = row_ptr3[r * N_NODES + n + 1];
        for (int i = beg; i < end; ++i) {
            int s = src_s[i];
            float4 nu = *reinterpret_cast<const float4*>(&numer[(size_t)i * HEADS]);
            float wv[HEADS] = {nu.x * di[0], nu.y * di[1], nu.z * di[2], nu.w * di[3]};
            float x0 = x[(size_t)s * DIM + lane];
            float x1 = x[(size_t)s * DIM + 64 + lane];
#pragma unroll
            for (int h = 0; h < HEADS; ++h) {
                acc[r][h][0] = fmaf(wv[h], x0, acc[r][h][0]);
                acc[r][h][1] = fmaf(wv[h], x1, acc[r][h][1]);
            }
        }
    }

    ushort_t* yr = y + (size_t)n * 1536;
#pragma unroll
    for (int h = 0; h < HEADS; ++h)
#pragma unroll
        for (int r = 0; r < NREL; ++r) {
            yr[h * 384 + r * 128 + lane]      = f2b(acc[r][h][0]);
            yr[h * 384 + r * 128 + 64 + lane] = f2b(acc[r][h][1]);
        }
}

// ---------------------------------------------------------------------------
extern "C" void kernel_launch(void* const* d_in, const int* in_sizes, int n_in,
                              void* d_out, int out_size, void* d_ws, size_t ws_size,
                              hipStream_t stream)
{
    const float* x   = (const float*)d_in[0];
    const float* WQ  = (const float*)d_in[1];
    const float* WK  = (const float*)d_in[2];
    const float* WV  = (const float*)d_in[3];
    const float* WO  = (const float*)d_in[4];
    const int*   src = (const int*)d_in[5];
    const int*   dst = (const int*)d_in[6];
    float* out = (float*)d_out;

    char* ws = (char*)d_ws;
    float*    scores   = (float*)(ws);                   // [0, 2.4M)
    float*    denom    = (float*)(ws + 2400000);         // 800,000
    int*      cnt3     = (int*)(ws + 3200000);           // 600,000
    int*      row_ptr3 = (int*)(ws + 3800000);           // 600,004 -> pad
    int*      cursor3  = (int*)(ws + 4400016);           // 600,000
    int*      src_s    = (int*)(ws + 5000016);           // 600,000
    int*      dst_s    = (int*)(ws + 5600016);           // 600,000
    int*      flagcnt  = (int*)(ws + 6200016);           // 16
    int*      fids     = (int*)(ws + 6200032);           // 131,072
    int*      blksum   = (int*)(ws + 6331104);           // 2,368
    int*      blkoff   = (int*)(ws + 6333472);           // 2,368
    ushort_t* WQt_hi   = (ushort_t*)(ws + 6335840);      // 131,072
    ushort_t* WQt_lo   = (ushort_t*)(ws + 6466912);      // 131,072
    ushort_t* WKt_hi   = (ushort_t*)(ws + 6597984);      // 393,216
    ushort_t* WKt_lo   = (ushort_t*)(ws + 6991200);      // 393,216
    ushort_t* W2t      = (ushort_t*)(ws + 7384416);      // 393,216 -> 7,777,632
    // big overlaid region:
    //   phase A: x_hi [7.78M, 20.58M) x_lo [20.58M, 33.38M) q4 [33.38M, 135.78M)
    //   phase B: y_cat [7.78M, 161.38M) bf16 [N][1536]
    ushort_t* x_hi  = (ushort_t*)(ws + 7777632);
    ushort_t* x_lo  = (ushort_t*)(ws + 20577632);
    float*    q4    = (float*)(ws + 33377632);
    ushort_t* y_cat = (ushort_t*)(ws + 7777632);

    dim3 blk(256);

    // ---- prep ----
    cvt_x_split<<<dim3(6250), blk, 0, stream>>>(x, x_hi, x_lo);
    transpose_cvt_split<<<dim3(16, 4), blk, 0, stream>>>(WQ, WQt_hi, WQt_lo, 128, 512);
    for (int r = 0; r < NREL; ++r)
        transpose_cvt_split<<<dim3(16, 4), blk, 0, stream>>>(WK + (size_t)r * DIM * HDIM,
                                                             WKt_hi + (size_t)r * HDIM * DIM,
                                                             WKt_lo + (size_t)r * HDIM * DIM, 128, 512);
    w2_kernel<<<dim3(768), blk, 0, stream>>>(WV, WO, W2t);

    hipMemsetAsync(cnt3,    0, (size_t)NKEYS * sizeof(int), stream);
    hipMemsetAsync(denom,   0, (size_t)N_NODES * HEADS * sizeof(float), stream);
    hipMemsetAsync(flagcnt, 0, 16, stream);

    // ---- per-rel CSR by dst (flattened keys) ----
    csr_count3<<<dim3((NETOT + 255) / 256), blk, 0, stream>>>(dst, cnt3);
    scan_blksum<<<dim3(NB2), blk, 0, stream>>>(cnt3, blksum);
    scan_top1024<<<dim3(1), dim3(1024), 0, stream>>>(blksum, blkoff, row_ptr3);
    scan_fin<<<dim3(NB2), blk, 0, stream>>>(cnt3, blkoff, row_ptr3, cursor3);
    csr_fill3<<<dim3((NETOT + 255) / 256), blk, 0, stream>>>(src, dst, cursor3, src_s, dst_s);

    const int MB128 = (N_NODES + 127) / 128;   // 391
    const int MB64  = (N_NODES + 63) / 64;     // 782

    // ---- q = x @ WQ (3-term split, head-major out) ----
    gemm_split_q<<<dim3(MB128, HEADS), blk, 0, stream>>>(x_hi, x_lo, WQt_hi, WQt_lo, q4, N_NODES);

    // ---- fused scores over sorted edges: (tile, head, rel) ----
    scores_v3<<<dim3(MB128, HEADS, NREL), blk, 0, stream>>>(
        x_hi, x_lo, WKt_hi, WKt_lo, q4, src_s, dst_s, scores, flagcnt, fids);

    // ---- exact f32 repair of near-zero scores ----
    repair_kernel<<<dim3(FLAG_CAP / 4), blk, 0, stream>>>(x, WQ, WK, src_s, dst_s,
                                                          flagcnt, fids, scores);

    // ---- numer (in place) + denom ----
    numer_denom<<<dim3((NETOT * HEADS + 255) / 256), blk, 0, stream>>>(scores, dst_s, denom);

    // ---- aggregation: all heads, per-rel CSR -> y_cat [N][1536] ----
    agg_all<<<dim3((N_NODES + 3) / 4), blk, 0, stream>>>(
        x, scores, denom, row_ptr3, src_s, y_cat);

    // ---- out = y_cat @ W2 ----
    gemm_mfma<0, 64><<<dim3(MB64, 1), blk, 0, stream>>>(y_cat, W2t, out, N_NODES, 1536, DIM);
}

// Round 9
// 434.393 us; speedup vs baseline: 1.2335x; 1.2335x over previous
//
#include <hip/hip_runtime.h>
#include <stdint.h>

// Problem constants (RelationalAttentionLayer)
#define N_NODES 50000
#define DIM     128
#define HEADS   4
#define HDIM    512      // HEADS * DIM
#define NREL    3
#define NEDGE   50000    // edges per relation
#define NETOT   150000   // total edges
#define FLAG_CAP 32768
#define NSCAN_BLK 196    // ceil(50000/256)

constexpr float EPS_F  = 1e-10f;
constexpr float SCALE  = 0.044194173824159216f;  // 1/sqrt(512)
constexpr float TAU    = 0.005f;                 // exact-repair band

typedef unsigned short ushort_t;
typedef __attribute__((ext_vector_type(8))) short  short8;
typedef __attribute__((ext_vector_type(4))) unsigned short ushort4v;
typedef __attribute__((ext_vector_type(4))) float  f32x4;

__device__ __forceinline__ float b2f(ushort_t u) {
    unsigned int v = ((unsigned int)u) << 16;
    float f; __builtin_memcpy(&f, &v, 4); return f;
}
__device__ __forceinline__ ushort_t f2b(float f) {
    unsigned int v; __builtin_memcpy(&v, &f, 4);
    unsigned int r = v + 0x7FFFu + ((v >> 16) & 1u);   // RNE
    return (ushort_t)(r >> 16);
}

#define LDSTRIDE 40   // ushort stride per 32-elem k-row (80B; 16B slots; 2-way alias free)

// ---------------------------------------------------------------------------
// bf16 MFMA GEMM (final out-GEMM): C[M,N] = A[M,K] @ Bt[N][K]^T. BM=64.
// ---------------------------------------------------------------------------
template <int OUTMODE, int BM>
__global__ __launch_bounds__(256) void gemm_mfma(const ushort_t* __restrict__ A,
                                                 const ushort_t* __restrict__ Bt,
                                                 void* __restrict__ Cv,
                                                 int M, int K, int ldc)
{
    constexpr int MFR = BM / 32;
    constexpr int ACH = BM * 4 / 256;

    __shared__ ushort_t As[BM * LDSTRIDE];
    __shared__ ushort_t Bs[128 * LDSTRIDE];

    const int tid = threadIdx.x;
    const int w = tid >> 6, l = tid & 63;
    const int bm = blockIdx.x, bn = blockIdx.y;
    const int wr = w >> 1, wc = w & 1;

    int sa_ro[ACH]; size_t sa_o[ACH];
#pragma unroll
    for (int i = 0; i < ACH; ++i) {
        int c = tid + 256 * i;
        int row = c >> 2, slot = c & 3;
        sa_ro[i] = row * LDSTRIDE + slot * 8;
        int grow = bm * BM + row; if (grow >= M) grow = M - 1;
        sa_o[i] = (size_t)grow * K + slot * 8;
    }
    int sb_ro[2]; size_t sb_o[2];
#pragma unroll
    for (int i = 0; i < 2; ++i) {
        int c = tid + 256 * i;
        int row = c >> 2, slot = c & 3;
        sb_ro[i] = row * LDSTRIDE + slot * 8;
        sb_o[i] = (size_t)(bn * 128 + row) * K + slot * 8;
    }

    int a_off[MFR], b_off[4];
#pragma unroll
    for (int mi = 0; mi < MFR; ++mi)
        a_off[mi] = (wr * (BM / 2) + mi * 16 + (l & 15)) * LDSTRIDE + (l >> 4) * 8;
#pragma unroll
    for (int ni = 0; ni < 4; ++ni)
        b_off[ni] = (wc * 64 + ni * 16 + (l & 15)) * LDSTRIDE + (l >> 4) * 8;

    f32x4 acc[MFR][4] = {};

    short8 av[ACH], bv[2];
#pragma unroll
    for (int i = 0; i < ACH; ++i) av[i] = *(const short8*)(A + sa_o[i]);
#pragma unroll
    for (int i = 0; i < 2; ++i)   bv[i] = *(const short8*)(Bt + sb_o[i]);

    for (int kk = 0; kk < K; kk += 32) {
        __syncthreads();
#pragma unroll
        for (int i = 0; i < ACH; ++i) *(short8*)&As[sa_ro[i]] = av[i];
#pragma unroll
        for (int i = 0; i < 2; ++i)   *(short8*)&Bs[sb_ro[i]] = bv[i];
        __syncthreads();

        if (kk + 32 < K) {
#pragma unroll
            for (int i = 0; i < ACH; ++i) av[i] = *(const short8*)(A + sa_o[i] + kk + 32);
#pragma unroll
            for (int i = 0; i < 2; ++i)   bv[i] = *(const short8*)(Bt + sb_o[i] + kk + 32);
        }

        short8 af[MFR], bfr[4];
#pragma unroll
        for (int mi = 0; mi < MFR; ++mi) af[mi]  = *(const short8*)&As[a_off[mi]];
#pragma unroll
        for (int ni = 0; ni < 4; ++ni)   bfr[ni] = *(const short8*)&Bs[b_off[ni]];

#pragma unroll
        for (int mi = 0; mi < MFR; ++mi)
#pragma unroll
            for (int ni = 0; ni < 4; ++ni)
                acc[mi][ni] = __builtin_amdgcn_mfma_f32_16x16x32_bf16(af[mi], bfr[ni], acc[mi][ni], 0, 0, 0);
    }

#pragma unroll
    for (int mi = 0; mi < MFR; ++mi)
#pragma unroll
        for (int j = 0; j < 4; ++j) {
            int row = bm * BM + wr * (BM / 2) + mi * 16 + (l >> 4) * 4 + j;
            if (row < M) {
#pragma unroll
                for (int ni = 0; ni < 4; ++ni) {
                    int col = bn * 128 + wc * 64 + ni * 16 + (l & 15);
                    if (OUTMODE == 1)
                        ((ushort_t*)Cv)[(size_t)row * ldc + col] = f2b(acc[mi][ni][j]);
                    else
                        ((float*)Cv)[(size_t)row * ldc + col] = acc[mi][ni][j];
                }
            }
        }
}

// ---------------------------------------------------------------------------
// M precompute: M[rh][d][d'] = sum_c WQ[d][h*128+c] * WK[r][d'][h*128+c]
// f32 accumulate, hi/lo bf16 split store. grid (128 d, 12 rh), 128 threads.
// ---------------------------------------------------------------------------
__global__ __launch_bounds__(128) void m_kernel(const float* __restrict__ WQ,
                                                const float* __restrict__ WK,
                                                ushort_t* __restrict__ M_hi,
                                                ushort_t* __restrict__ M_lo)
{
    __shared__ float wq[128];
    const int d  = blockIdx.x;
    const int rh = blockIdx.y;
    const int r = rh >> 2, h = rh & 3;
    const int t = threadIdx.x;   // d' = t

    wq[t] = WQ[(size_t)d * HDIM + h * DIM + t];
    __syncthreads();

    const float* wk = WK + (size_t)r * DIM * HDIM + (size_t)t * HDIM + h * DIM;
    float acc = 0.f;
#pragma unroll 4
    for (int c = 0; c < DIM; ++c)
        acc = fmaf(wq[c], wk[c], acc);

    size_t o = (size_t)rh * 16384 + d * 128 + t;
    ushort_t hv = f2b(acc);
    M_hi[o] = hv;
    M_lo[o] = f2b(acc - b2f(hv));
}

// ---------------------------------------------------------------------------
// Bilinear fused scores, ONE launch: grid (edge-tile, head, rel). Per block:
//   G = (x_hi+x_lo)[src] @ M_rh^T  (3-term split MFMA; M hi/lo staged to LDS)
//   s[e,h] = SCALE * dot(x_f32[dst], G[e,:]);   flag |s|<TAU for exact repair.
// Working set: x pools (51 MB) + M (1.5 MB) -- L2/L3-resident; q eliminated.
// ---------------------------------------------------------------------------
__global__ __launch_bounds__(256) void scores_bilin(const ushort_t* __restrict__ xh,
                                                    const ushort_t* __restrict__ xl,
                                                    const ushort_t* __restrict__ M_hi,
                                                    const ushort_t* __restrict__ M_lo,
                                                    const float* __restrict__ x,
                                                    const int* __restrict__ src,
                                                    const int* __restrict__ dst,
                                                    float* __restrict__ scores,
                                                    int* __restrict__ flagcnt,
                                                    int* __restrict__ fids)
{
    __shared__ ushort_t Ah[128 * LDSTRIDE], Al[128 * LDSTRIDE];
    __shared__ ushort_t Bh[128 * LDSTRIDE], Bl[128 * LDSTRIDE];
    __shared__ float sc_red[128][2];

    const int tid = threadIdx.x;
    const int w = tid >> 6, l = tid & 63;
    const int bm = blockIdx.x;
    const int nc = blockIdx.y;          // head
    const int r  = blockIdx.z;          // relation
    const int wr = w >> 1, wc = w & 1;

    const int* srcr = src + r * NEDGE;
    const int* dstr = dst + r * NEDGE;
    const ushort_t* Wh = M_hi + (size_t)(r * 4 + nc) * 16384;
    const ushort_t* Wl = M_lo + (size_t)(r * 4 + nc) * 16384;
    float* sc_out = scores + (size_t)r * NEDGE * HEADS;

    int s_ro[2]; size_t s_ao[2], s_bo[2];
#pragma unroll
    for (int i = 0; i < 2; ++i) {
        int c = tid + 256 * i;
        int row = c >> 2, slot = c & 3;
        s_ro[i] = row * LDSTRIDE + slot * 8;
        int e = bm * 128 + row; if (e >= NEDGE) e = NEDGE - 1;
        s_ao[i] = (size_t)srcr[e] * 128 + slot * 8;
        s_bo[i] = (size_t)row * 128 + slot * 8;     // M is [128][128]
    }

    int a_off[4], b_off[4];
#pragma unroll
    for (int mi = 0; mi < 4; ++mi)
        a_off[mi] = (wr * 64 + mi * 16 + (l & 15)) * LDSTRIDE + (l >> 4) * 8;
#pragma unroll
    for (int ni = 0; ni < 4; ++ni)
        b_off[ni] = (wc * 64 + ni * 16 + (l & 15)) * LDSTRIDE + (l >> 4) * 8;

    f32x4 acc[4][4] = {};

    // prefetch k-slice 0
    short8 vah[2], val[2], vbh[2], vbl[2];
#pragma unroll
    for (int i = 0; i < 2; ++i) {
        vah[i] = *(const short8*)(xh + s_ao[i]);
        val[i] = *(const short8*)(xl + s_ao[i]);
        vbh[i] = *(const short8*)(Wh + s_bo[i]);
        vbl[i] = *(const short8*)(Wl + s_bo[i]);
    }

    for (int kk = 0; kk < 128; kk += 32) {
        __syncthreads();
#pragma unroll
        for (int i = 0; i < 2; ++i) {
            *(short8*)&Ah[s_ro[i]] = vah[i];
            *(short8*)&Al[s_ro[i]] = val[i];
            *(short8*)&Bh[s_ro[i]] = vbh[i];
            *(short8*)&Bl[s_ro[i]] = vbl[i];
        }
        __syncthreads();

        if (kk + 32 < 128) {
#pragma unroll
            for (int i = 0; i < 2; ++i) {
                vah[i] = *(const short8*)(xh + s_ao[i] + kk + 32);
                val[i] = *(const short8*)(xl + s_ao[i] + kk + 32);
                vbh[i] = *(const short8*)(Wh + s_bo[i] + kk + 32);
                vbl[i] = *(const short8*)(Wl + s_bo[i] + kk + 32);
            }
        }

        short8 ah[4], al[4], bh[4], bl[4];
#pragma unroll
        for (int mi = 0; mi < 4; ++mi) { ah[mi] = *(const short8*)&Ah[a_off[mi]];
                                         al[mi] = *(const short8*)&Al[a_off[mi]]; }
#pragma unroll
        for (int ni = 0; ni < 4; ++ni) { bh[ni] = *(const short8*)&Bh[b_off[ni]];
                                         bl[ni] = *(const short8*)&Bl[b_off[ni]]; }
#pragma unroll
        for (int mi = 0; mi < 4; ++mi)
#pragma unroll
            for (int ni = 0; ni < 4; ++ni) {
                acc[mi][ni] = __builtin_amdgcn_mfma_f32_16x16x32_bf16(ah[mi], bh[ni], acc[mi][ni], 0, 0, 0);
                acc[mi][ni] = __builtin_amdgcn_mfma_f32_16x16x32_bf16(ah[mi], bl[ni], acc[mi][ni], 0, 0, 0);
                acc[mi][ni] = __builtin_amdgcn_mfma_f32_16x16x32_bf16(al[mi], bh[ni], acc[mi][ni], 0, 0, 0);
            }
    }

    // dot G-fragments with x_f32[dst]
#pragma unroll
    for (int mi = 0; mi < 4; ++mi)
#pragma unroll
        for (int j = 0; j < 4; ++j) {
            int e_loc = wr * 64 + mi * 16 + (l >> 4) * 4 + j;
            int e = bm * 128 + e_loc; int ec = (e < NEDGE) ? e : NEDGE - 1;
            int d = dstr[ec];
            const float* xr = x + (size_t)d * DIM + wc * 64 + (l & 15);
            float p = acc[mi][0][j] * xr[0]  + acc[mi][1][j] * xr[16]
                    + acc[mi][2][j] * xr[32] + acc[mi][3][j] * xr[48];
            p += __shfl_xor(p, 1); p += __shfl_xor(p, 2);
            p += __shfl_xor(p, 4); p += __shfl_xor(p, 8);
            if ((l & 15) == 0) sc_red[e_loc][wc] = p;
        }
    __syncthreads();

    if (tid < 128) {
        int e = bm * 128 + tid;
        if (e < NEDGE) {
            float s = (sc_red[tid][0] + sc_red[tid][1]) * SCALE;
            sc_out[(size_t)e * HEADS + nc] = s;
            if (fabsf(s) < TAU) {
                int pos = atomicAdd(flagcnt, 1);
                if (pos < FLAG_CAP) fids[pos] = (r * NEDGE + e) * HEADS + nc;
            }
        }
    }
}

// ---------------------------------------------------------------------------
// Exact f32 repair of near-zero scores (original edge-order indexing).
// ---------------------------------------------------------------------------
__global__ __launch_bounds__(256) void repair_kernel(const float* __restrict__ x,
                                                     const float* __restrict__ WQ,
                                                     const float* __restrict__ WK,
                                                     const int* __restrict__ src,
                                                     const int* __restrict__ dst,
                                                     const int* __restrict__ flagcnt,
                                                     const int* __restrict__ fids,
                                                     float* __restrict__ scores)
{
    int wid = blockIdx.x * 4 + (threadIdx.x >> 6);
    int l = threadIdx.x & 63;
    int nf = *flagcnt; if (nf > FLAG_CAP) nf = FLAG_CAP;
    if (wid >= nf) return;
    int p = fids[wid];
    int h = p & 3; int eg = p >> 2; int r = eg / NEDGE;
    int s = src[eg], d = dst[eg];
    const float* xs = x + (size_t)s * DIM;
    const float* xd = x + (size_t)d * DIM;
    const float* wq = WQ + h * DIM;
    const float* wk = WK + (size_t)r * DIM * HDIM + h * DIM;

    float tot = 0.f;
#pragma unroll 1
    for (int j = 0; j < 2; ++j) {
        int c = j * 64 + l;
        float qc = 0.f, kc = 0.f;
        for (int dd = 0; dd < DIM; ++dd) {
            qc = fmaf(xd[dd], wq[(size_t)dd * HDIM + c], qc);
            kc = fmaf(xs[dd], wk[(size_t)dd * HDIM + c], kc);
        }
        tot = fmaf(qc, kc, tot);
    }
    tot += __shfl_xor(tot, 1);  tot += __shfl_xor(tot, 2);
    tot += __shfl_xor(tot, 4);  tot += __shfl_xor(tot, 8);
    tot += __shfl_xor(tot, 16); tot += __shfl_xor(tot, 32);
    if (l == 0) scores[p] = tot * SCALE;
}

// ---------------------------------------------------------------------------
// numer = relu(s)^2 + eps (in place) ; atomic denom
// ---------------------------------------------------------------------------
__global__ __launch_bounds__(256) void numer_denom(float* __restrict__ scores,
                                                   const int* __restrict__ dst,
                                                   float* __restrict__ denom)
{
    int p = blockIdx.x * 256 + threadIdx.x;
    if (p < NETOT * HEADS) {
        float s = scores[p];
        float m = fmaxf(s, 0.f);
        float nu = m * m + EPS_F;
        scores[p] = nu;
        atomicAdd(&denom[dst[p >> 2] * HEADS + (p & 3)], nu);
    }
}

// ---------------------------------------------------------------------------
// prep: x -> bf16 hi/lo split
// ---------------------------------------------------------------------------
__global__ __launch_bounds__(256) void cvt_x_split(const float* __restrict__ x,
                                                   ushort_t* __restrict__ xh,
                                                   ushort_t* __restrict__ xl)
{
    int i = (blockIdx.x * 256 + threadIdx.x) * 4;
    float4 v = *reinterpret_cast<const float4*>(x + i);
    ushort_t h0 = f2b(v.x), h1 = f2b(v.y), h2 = f2b(v.z), h3 = f2b(v.w);
    ushort4v oh = {h0, h1, h2, h3};
    ushort4v ol = {f2b(v.x - b2f(h0)), f2b(v.y - b2f(h1)),
                   f2b(v.z - b2f(h2)), f2b(v.w - b2f(h3))};
    *reinterpret_cast<ushort4v*>(xh + i) = oh;
    *reinterpret_cast<ushort4v*>(xl + i) = ol;
}

// ---------------------------------------------------------------------------
// W2 composite: W2t[j][h*384 + r*128 + d] = sum_c WV[r][d][h*128+c] * WO[h*128+c][j]
// ---------------------------------------------------------------------------
__global__ __launch_bounds__(256) void w2_kernel(const float* __restrict__ WV,
                                                 const float* __restrict__ WO,
                                                 ushort_t* __restrict__ W2t)
{
    int j = threadIdx.x & 127;
    int hk = blockIdx.x * 2 + (threadIdx.x >> 7);   // 0..1535
    int h = hk / 384, kk = hk % 384;
    int r = kk >> 7, d = kk & 127;
    const float* wv = WV + (size_t)r * DIM * HDIM + (size_t)d * HDIM + h * DIM;
    const float* wo = WO + (size_t)(h * DIM) * DIM + j;
    float acc = 0.f;
#pragma unroll 4
    for (int c = 0; c < DIM; ++c)
        acc = fmaf(wv[c], wo[(size_t)c * DIM], acc);
    W2t[(size_t)j * 1536 + hk] = f2b(acc);
}

// ---------------------------------------------------------------------------
// CSR build (single dst key): count, hierarchical scan, fill.
// ---------------------------------------------------------------------------
__global__ __launch_bounds__(256) void csr_count(const int* __restrict__ dst, int* __restrict__ cnt)
{
    int e = blockIdx.x * 256 + threadIdx.x;
    if (e < NETOT) atomicAdd(&cnt[dst[e]], 1);
}

__global__ __launch_bounds__(256) void scan_blksum(const int* __restrict__ cnt,
                                                   int* __restrict__ blksum)
{
    __shared__ int red[4];
    int tid = threadIdx.x, lane = tid & 63, wave = tid >> 6;
    int i = blockIdx.x * 256 + tid;
    int v = (i < N_NODES) ? cnt[i] : 0;
#pragma unroll
    for (int off = 32; off > 0; off >>= 1) v += __shfl_down(v, off);
    if (lane == 0) red[wave] = v;
    __syncthreads();
    if (tid == 0) blksum[blockIdx.x] = red[0] + red[1] + red[2] + red[3];
}

__global__ __launch_bounds__(256) void scan_top(const int* __restrict__ blksum,
                                                int* __restrict__ blkoff,
                                                int* __restrict__ row_ptr)
{
    __shared__ int s[256];
    int t = threadIdx.x;
    int v = (t < NSCAN_BLK) ? blksum[t] : 0;
    s[t] = v;
    __syncthreads();
    for (int off = 1; off < 256; off <<= 1) {
        int u = (t >= off) ? s[t - off] : 0;
        __syncthreads();
        s[t] += u;
        __syncthreads();
    }
    if (t < NSCAN_BLK) blkoff[t] = s[t] - v;   // exclusive
    if (t == NSCAN_BLK - 1) row_ptr[N_NODES] = s[t];
}

__global__ __launch_bounds__(256) void scan_fin(const int* __restrict__ cnt,
                                                const int* __restrict__ blkoff,
                                                int* __restrict__ row_ptr,
                                                int* __restrict__ cursor)
{
    __shared__ int s[256];
    int t = threadIdx.x, i = blockIdx.x * 256 + t;
    int v = (i < N_NODES) ? cnt[i] : 0;
    s[t] = v;
    __syncthreads();
    for (int off = 1; off < 256; off <<= 1) {
        int u = (t >= off) ? s[t - off] : 0;
        __syncthreads();
        s[t] += u;
        __syncthreads();
    }
    if (i < N_NODES) {
        int val = blkoff[blockIdx.x] + s[t] - v;
        row_ptr[i] = val;
        cursor[i]  = val;
    }
}

__global__ __launch_bounds__(256) void csr_fill(const int* __restrict__ dst,
                                                int* __restrict__ cursor,
                                                int* __restrict__ eids)
{
    int e = blockIdx.x * 256 + threadIdx.x;
    if (e < NETOT) {
        int pos = atomicAdd(&cursor[dst[e]], 1);
        eids[pos] = e;
    }
}

// ---------------------------------------------------------------------------
// agg_all: one wave per node, ALL 4 heads in one pass (x gathered once).
// ---------------------------------------------------------------------------
__global__ __launch_bounds__(256) void agg_all(const float* __restrict__ x,
                                               const float* __restrict__ numer,
                                               const float* __restrict__ denom,
                                               const int* __restrict__ row_ptr,
                                               const int* __restrict__ eids,
                                               const int* __restrict__ src,
                                               ushort_t* __restrict__ y)
{
    const int wave = threadIdx.x >> 6, lane = threadIdx.x & 63;
    const int n = blockIdx.x * 4 + wave;
    if (n >= N_NODES) return;

    const int beg = row_ptr[n], end = row_ptr[n + 1];
    float acc[NREL][HEADS][2] = {};

    if (beg < end) {
        float4 dn = *reinterpret_cast<const float4*>(&denom[n * HEADS]);
        float di[HEADS] = {1.f / dn.x, 1.f / dn.y, 1.f / dn.z, 1.f / dn.w};
        for (int i = beg; i < end; ++i) {
            int e = eids[i];
            int s = src[e];
            float4 nu = *reinterpret_cast<const float4*>(&numer[(size_t)e * HEADS]);
            float wv[HEADS] = {nu.x * di[0], nu.y * di[1], nu.z * di[2], nu.w * di[3]};
            float x0 = x[(size_t)s * DIM + lane];
            float x1 = x[(size_t)s * DIM + 64 + lane];
            int r = e / NEDGE;   // wave-uniform per iteration
            if (r == 0) {
#pragma unroll
                for (int h = 0; h < HEADS; ++h) {
                    acc[0][h][0] = fmaf(wv[h], x0, acc[0][h][0]);
                    acc[0][h][1] = fmaf(wv[h], x1, acc[0][h][1]);
                }
            } else if (r == 1) {
#pragma unroll
                for (int h = 0; h < HEADS; ++h) {
                    acc[1][h][0] = fmaf(wv[h], x0, acc[1][h][0]);
                    acc[1][h][1] = fmaf(wv[h], x1, acc[1][h][1]);
                }
            } else {
#pragma unroll
                for (int h = 0; h < HEADS; ++h) {
                    acc[2][h][0] = fmaf(wv[h], x0, acc[2][h][0]);
                    acc[2][h][1] = fmaf(wv[h], x1, acc[2][h][1]);
                }
            }
        }
    }

    ushort_t* yr = y + (size_t)n * 1536;
#pragma unroll
    for (int h = 0; h < HEADS; ++h)
#pragma unroll
        for (int r = 0; r < NREL; ++r) {
            yr[h * 384 + r * 128 + lane]      = f2b(acc[r][h][0]);
            yr[h * 384 + r * 128 + 64 + lane] = f2b(acc[r][h][1]);
        }
}

// ---------------------------------------------------------------------------
extern "C" void kernel_launch(void* const* d_in, const int* in_sizes, int n_in,
                              void* d_out, int out_size, void* d_ws, size_t ws_size,
                              hipStream_t stream)
{
    const float* x   = (const float*)d_in[0];
    const float* WQ  = (const float*)d_in[1];
    const float* WK  = (const float*)d_in[2];
    const float* WV  = (const float*)d_in[3];
    const float* WO  = (const float*)d_in[4];
    const int*   src = (const int*)d_in[5];
    const int*   dst = (const int*)d_in[6];
    float* out = (float*)d_out;

    char* ws = (char*)d_ws;
    float*    scores  = (float*)(ws);                    // 2,400,000 (later numer in place)
    float*    denom   = (float*)(ws + 2400000);          //   800,000
    int*      cnt     = (int*)(ws + 3200000);            //   200,000
    int*      row_ptr = (int*)(ws + 3400000);            //   200,004 -> pad
    int*      cursor  = (int*)(ws + 3600016);            //   200,000
    int*      eids    = (int*)(ws + 3800016);            //   600,000
    int*      flagcnt = (int*)(ws + 4400016);            //        16
    int*      fids    = (int*)(ws + 4400032);            //   131,072
    int*      blksum  = (int*)(ws + 4531104);            //     ~1040
    int*      blkoff  = (int*)(ws + 4532144);            //     ~1040
    ushort_t* M_hi    = (ushort_t*)(ws + 4533184);       //   393,216 [12][128][128]
    ushort_t* M_lo    = (ushort_t*)(ws + 4926400);       //   393,216
    ushort_t* W2t     = (ushort_t*)(ws + 5319616);       //   393,216 -> 5,712,832
    // big overlaid region, base 5,712,832:
    //   phase A: x_hi [5.71M, 18.51M) x_lo [18.51M, 31.31M)
    //   phase B: y_cat [5.71M, 159.31M) bf16 [N][1536]  (x_hi/x_lo dead after scores)
    ushort_t* x_hi  = (ushort_t*)(ws + 5712832);
    ushort_t* x_lo  = (ushort_t*)(ws + 18512832);
    ushort_t* y_cat = (ushort_t*)(ws + 5712832);

    dim3 blk(256);

    // ---- prep ----
    cvt_x_split<<<dim3(6250), blk, 0, stream>>>(x, x_hi, x_lo);
    m_kernel<<<dim3(128, 12), dim3(128), 0, stream>>>(WQ, WK, M_hi, M_lo);
    w2_kernel<<<dim3(768), blk, 0, stream>>>(WV, WO, W2t);

    hipMemsetAsync(cnt,     0, (size_t)N_NODES * sizeof(int), stream);
    hipMemsetAsync(denom,   0, (size_t)N_NODES * HEADS * sizeof(float), stream);
    hipMemsetAsync(flagcnt, 0, 16, stream);

    // ---- CSR by dst (parallel scan) ----
    csr_count<<<dim3((NETOT + 255) / 256), blk, 0, stream>>>(dst, cnt);
    scan_blksum<<<dim3(NSCAN_BLK), blk, 0, stream>>>(cnt, blksum);
    scan_top<<<dim3(1), blk, 0, stream>>>(blksum, blkoff, row_ptr);
    scan_fin<<<dim3(NSCAN_BLK), blk, 0, stream>>>(cnt, blkoff, row_ptr, cursor);
    csr_fill<<<dim3((NETOT + 255) / 256), blk, 0, stream>>>(dst, cursor, eids);

    const int MB128 = (N_NODES + 127) / 128;   // 391
    const int MB64  = (N_NODES + 63) / 64;     // 782

    // ---- bilinear fused scores: single launch over (edge-tile, head, rel) ----
    scores_bilin<<<dim3(MB128, HEADS, NREL), blk, 0, stream>>>(
        x_hi, x_lo, M_hi, M_lo, x, src, dst, scores, flagcnt, fids);

    // ---- exact f32 repair of near-zero scores ----
    repair_kernel<<<dim3(FLAG_CAP / 4), blk, 0, stream>>>(x, WQ, WK, src, dst,
                                                          flagcnt, fids, scores);

    // ---- numer (in place) + denom ----
    numer_denom<<<dim3((NETOT * HEADS + 255) / 256), blk, 0, stream>>>(scores, dst, denom);

    // ---- aggregation: all 4 heads in one pass -> y_cat [N][1536] ----
    agg_all<<<dim3((N_NODES + 3) / 4), blk, 0, stream>>>(
        x, scores, denom, row_ptr, eids, src, y_cat);

    // ---- out = y_cat @ W2 (one MFMA GEMM, BM=64) ----
    gemm_mfma<0, 64><<<dim3(MB64, 1), blk, 0, stream>>>(y_cat, W2t, out, N_NODES, 1536, DIM);
}